// Round 14
// baseline (15188.582 us; speedup 1.0000x reference)
//
#include <hip/hip_runtime.h>
#include <cstdint>

// GRU persistent kernel v12 (resubmit; round-13 bench died to the recurring
// UnresponsiveContainer infra error before producing data — same failure as
// rounds 0/10, and round 10's kernel ran fine on unchanged resubmit):
// T=512, B=64, I=512, H=1024, O=512, fp32.
// 256 blocks (1/CU, ALL resident -> single barrier group, no serialization)
// x 1024 threads = 16 waves/CU = 4 waves/SIMD. 1024-thr blocks always get a
// 64-VGPR budget (v4/v5/v6), so the kernel is DESIGNED for it: 4 j-cols per
// block, 16 k/thread, no cross-phase stashes (h re-read per phase via
// chunked coherent loads; the A2 re-read overlaps barrier A), accumulators
// <=24 floats, phase C split into 3 single-gate passes.
// sc0/sc1 fence-free coherent h/s exchange + relaxed single-group barrier
// (v9/v10-validated protocol). Weights for all 3 h-gates in 48 KB swizzled
// LDS; x-weights pre-transposed [j][k]; W_out streamed (L2-hot).
// Phases per step:
//   A : r = sigmoid(h@W_rh + xr_pre + b_r); s = r*h        -> arrive(A)
//   A2: z = sigmoid(h@W_zh + xz_pre + b_z); y_{t-1}=h@Wout -> wait(A)
//   B : ht = tanh(s@W_hh + xh_pre + b_h); h += z*(ht-h)    -> arrive(B)
//   C : xr/xz/xh_pre for step t+1 (x only, hides barrier B) -> wait(B)

#define TT 512
#define BB 64
#define II 512
#define HH 1024
#define OO 512
#define NTHR 1024
#define NBLK 256
#define RSTR 528

typedef float4 f4;
__device__ __forceinline__ f4 ld4(const float* p){ return *reinterpret_cast<const f4*>(p); }
// per-wave weight addresses: kh0 base + {0,16,32,48} (+i4*4). swz XORs float
// idx bits[4:2] with k bits[6:4] -> the 4 b128 reads land on 4 distinct bank
// quads: conflict-free.
__device__ __forceinline__ int swz(int k){ return k ^ (((k >> 4) & 7) << 2); }

// ---- coherent (L2-bypass, L3-served) access helpers for h/s ----
// 4 consecutive-k f4 loads (k-row stride BB*4 = 256 B), single vmcnt.
// Chunked 4-deep (not 16) to cap transient VGPR at 16 under the 64-reg budget.
__device__ __forceinline__ void ldc4(const float* p, f4* d){
  asm volatile(
    "global_load_dwordx4 %0, %4, off sc0 sc1\n\t"
    "global_load_dwordx4 %1, %4, off offset:256 sc0 sc1\n\t"
    "global_load_dwordx4 %2, %4, off offset:512 sc0 sc1\n\t"
    "global_load_dwordx4 %3, %4, off offset:768 sc0 sc1\n\t"
    "s_waitcnt vmcnt(0)"
    : "=&v"(d[0]),"=&v"(d[1]),"=&v"(d[2]),"=&v"(d[3])
    : "v"(p) : "memory");
}
__device__ __forceinline__ float ldc1(const float* p){
  float v;
  asm volatile("global_load_dword %0, %1, off sc0 sc1\n\ts_waitcnt vmcnt(0)"
               : "=v"(v) : "v"(p) : "memory");
  return v;
}
__device__ __forceinline__ void stc1(float* p, float v){
  asm volatile("global_store_dword %0, %1, off sc0 sc1" :: "v"(p), "v"(v) : "memory");
}

// ---------------- one-time prep kernels ----------------
__global__ void k_transpose_x(const float* __restrict__ x, float* __restrict__ xT){
  size_t total = (size_t)TT * II * BB;
  for (size_t n = (size_t)blockIdx.x * blockDim.x + threadIdx.x; n < total;
       n += (size_t)gridDim.x * blockDim.x){
    size_t t = n / ((size_t)II * BB);
    size_t rem = n % ((size_t)II * BB);
    size_t i = rem / BB, b = rem % BB;
    xT[n] = x[(t * BB + b) * II + i];
  }
}

__global__ void k_transpose_wx(const float* __restrict__ W, float* __restrict__ WT){
  size_t n = (size_t)blockIdx.x * blockDim.x + threadIdx.x;
  if (n >= (size_t)II * HH) return;
  size_t j = n / II, k = n % II;
  WT[n] = W[k * HH + j];
}

__global__ void k_transpose_h0(const float* __restrict__ st, float* __restrict__ h0){
  size_t n = (size_t)blockIdx.x * blockDim.x + threadIdx.x;
  if (n >= (size_t)HH * BB) return;
  size_t j = n / BB, b = n % BB;
  h0[n] = st[b * HH + j];
}

__global__ void k_init_bars(unsigned* bars){
  if (threadIdx.x < 512) bars[threadIdx.x] = 0;
}

// --- barrier: ONE group of 256 blocks; 16 leaves x 16 arrivals; RELAXED ---
__device__ __forceinline__ void g_arrive(unsigned* bars, int bid, unsigned ep){
  asm volatile("s_waitcnt vmcnt(0)" ::: "memory");   // drain sc1 data stores
  unsigned* leaf = bars + (bid & 15) * 16;
  unsigned old = __hip_atomic_fetch_add(leaf, 1u, __ATOMIC_RELAXED, __HIP_MEMORY_SCOPE_AGENT);
  if (old + 1u == ep * 16u)
    __hip_atomic_fetch_add(bars + 256, 1u, __ATOMIC_RELAXED, __HIP_MEMORY_SCOPE_AGENT);
}
__device__ __forceinline__ void g_wait(unsigned* bars, unsigned ep){
  while (__hip_atomic_load(bars + 256, __ATOMIC_RELAXED, __HIP_MEMORY_SCOPE_AGENT) < ep * 16u)
    __builtin_amdgcn_s_sleep(1);
}

// in-wave ksec bits = tid bits [5:4] -> reduce over lanes xor 16, 32
#define WREDUCE(v) { v += __shfl_xor(v, 16); v += __shfl_xor(v, 32); }

// ---------------- the persistent GRU kernel ----------------
__global__ __launch_bounds__(NTHR) void k_gru(
    const float* __restrict__ xT,
    const float* __restrict__ WxTr, const float* __restrict__ WxTz, const float* __restrict__ WxTh,
    float* __restrict__ h, float* __restrict__ s,
    const float* __restrict__ W_zh, const float* __restrict__ b_z,
    const float* __restrict__ W_rh, const float* __restrict__ b_r,
    const float* __restrict__ W_hh, const float* __restrict__ b_h,
    const float* __restrict__ W_out, const float* __restrict__ b_out,
    float* __restrict__ out, unsigned* __restrict__ bars)
{
  __shared__ float sW[3 * 4 * 1024];   // [0=RH,1=ZH,2=HH][c<4][k swz]  48 KB
  __shared__ float red[16 * RSTR];     // cross-wave reduce             33.8 KB
  __shared__ float xpre[3][256];       // x-projections (4c x 64b)
  __shared__ float sZ[256];            // z gate
  __shared__ float sBias[16];          // b_r[4] b_z[4] b_h[4] b_out[2]

  const int tid = threadIdx.x;
  const int bid = blockIdx.x;
  const int j0 = bid * 4, o0 = bid * 2;

  // ---- prologue: weight slices -> swizzled LDS (one k per thread) ----
  {
    const int k = tid;                 // 0..1023
    f4 vr = ld4(W_rh + (size_t)k * HH + j0);
    f4 vz = ld4(W_zh + (size_t)k * HH + j0);
    f4 vh = ld4(W_hh + (size_t)k * HH + j0);
    const int kx = swz(k);
    float ar[4] = {vr.x,vr.y,vr.z,vr.w};
    float az[4] = {vz.x,vz.y,vz.z,vz.w};
    float ah[4] = {vh.x,vh.y,vh.z,vh.w};
    #pragma unroll
    for (int c = 0; c < 4; ++c){
      sW[0*4096 + c*1024 + kx] = ar[c];
      sW[1*4096 + c*1024 + kx] = az[c];
      sW[2*4096 + c*1024 + kx] = ah[c];
    }
  }
  if (tid < 4){
    sBias[tid]     = b_r[j0 + tid];
    sBias[4 + tid] = b_z[j0 + tid];
    sBias[8 + tid] = b_h[j0 + tid];
    if (tid < 2) sBias[12 + tid] = b_out[o0 + tid];
  }

  const int bg = tid & 15, b0 = bg * 4;      // 16 groups x 4 b = full 64
  const int ksec = tid >> 4;                 // 0..63
  const int wv = tid >> 6;                   // wave 0..15
  const bool wr0 = ((tid & 48) == 0);        // in-wave ksec bits == 0
  const int kh0 = ksec * 16;                 // K=1024 / 64
  const int kx0 = ksec * 8;                  // K=512  / 64
  __syncthreads();

  for (int t = -1; t < TT; ++t){
    if (t >= 0){
      const float* hb = h + kh0 * BB + b0;

      // ================= A: r gate =================
      {
        float aR[4][4] = {};
        #pragma unroll
        for (int i4 = 0; i4 < 4; ++i4){
          f4 hv4[4];
          ldc4(hb + i4*4*BB, hv4);
          const int kxc = swz(kh0 + i4*4);
          #pragma unroll
          for (int c = 0; c < 4; ++c){
            f4 wf = *reinterpret_cast<const f4*>(&sW[0*4096 + c*1024 + kxc]);
            float wvv[4] = {wf.x, wf.y, wf.z, wf.w};
            #pragma unroll
            for (int kk = 0; kk < 4; ++kk){
              const f4 hv = hv4[kk];
              aR[c][0] = fmaf(wvv[kk], hv.x, aR[c][0]);
              aR[c][1] = fmaf(wvv[kk], hv.y, aR[c][1]);
              aR[c][2] = fmaf(wvv[kk], hv.z, aR[c][2]);
              aR[c][3] = fmaf(wvv[kk], hv.w, aR[c][3]);
            }
          }
        }
        #pragma unroll
        for (int c = 0; c < 4; ++c)
          #pragma unroll
          for (int bb = 0; bb < 4; ++bb) WREDUCE(aR[c][bb]);
        if (wr0)
          #pragma unroll
          for (int c = 0; c < 4; ++c)
            #pragma unroll
            for (int bb = 0; bb < 4; ++bb)
              red[wv*RSTR + c*64 + b0 + bb] = aR[c][bb];
      }
      __syncthreads();
      if (tid < 256){
        float sum = 0.f;
        #pragma unroll
        for (int w = 0; w < 16; ++w) sum += red[w*RSTR + tid];
        const int c = tid >> 6, bl = tid & 63;
        const float v = sum + xpre[0][tid] + sBias[c];
        const float rr = 1.f / (1.f + expf(-v));
        const int jg = j0 + c;
        stc1(&s[jg*BB + bl], rr * ldc1(&h[jg*BB + bl]));
      }
      __syncthreads();
      if (tid == 0) g_arrive(bars, bid, 2*t + 1);

      // ========== A2: z gate + y_{t-1} (h re-read overlaps barrier A) ==========
      {
        float aZ[4][4] = {};
        float aY[2][4] = {};
        #pragma unroll
        for (int i4 = 0; i4 < 4; ++i4){
          f4 hv4[4];
          ldc4(hb + i4*4*BB, hv4);
          const int kc = kh0 + i4*4;
          const int kxc = swz(kc);
          #pragma unroll
          for (int c = 0; c < 4; ++c){
            f4 wf = *reinterpret_cast<const f4*>(&sW[1*4096 + c*1024 + kxc]);
            float wvv[4] = {wf.x, wf.y, wf.z, wf.w};
            #pragma unroll
            for (int kk = 0; kk < 4; ++kk){
              const f4 hv = hv4[kk];
              aZ[c][0] = fmaf(wvv[kk], hv.x, aZ[c][0]);
              aZ[c][1] = fmaf(wvv[kk], hv.y, aZ[c][1]);
              aZ[c][2] = fmaf(wvv[kk], hv.z, aZ[c][2]);
              aZ[c][3] = fmaf(wvv[kk], hv.w, aZ[c][3]);
            }
          }
          #pragma unroll
          for (int oc = 0; oc < 2; ++oc){
            f4 wo = ld4(W_out + (size_t)(o0 + oc) * HH + kc);   // L2-hot
            float wvv[4] = {wo.x, wo.y, wo.z, wo.w};
            #pragma unroll
            for (int kk = 0; kk < 4; ++kk){
              const f4 hv = hv4[kk];
              aY[oc][0] = fmaf(wvv[kk], hv.x, aY[oc][0]);
              aY[oc][1] = fmaf(wvv[kk], hv.y, aY[oc][1]);
              aY[oc][2] = fmaf(wvv[kk], hv.z, aY[oc][2]);
              aY[oc][3] = fmaf(wvv[kk], hv.w, aY[oc][3]);
            }
          }
        }
        #pragma unroll
        for (int c = 0; c < 4; ++c)
          #pragma unroll
          for (int bb = 0; bb < 4; ++bb) WREDUCE(aZ[c][bb]);
        #pragma unroll
        for (int oc = 0; oc < 2; ++oc)
          #pragma unroll
          for (int bb = 0; bb < 4; ++bb) WREDUCE(aY[oc][bb]);
        if (wr0){
          #pragma unroll
          for (int c = 0; c < 4; ++c)
            #pragma unroll
            for (int bb = 0; bb < 4; ++bb)
              red[wv*RSTR + c*64 + b0 + bb] = aZ[c][bb];
          #pragma unroll
          for (int oc = 0; oc < 2; ++oc)
            #pragma unroll
            for (int bb = 0; bb < 4; ++bb)
              red[wv*RSTR + 256 + oc*64 + b0 + bb] = aY[oc][bb];
        }
      }
      __syncthreads();
      if (tid < 256){
        float sum = 0.f;
        #pragma unroll
        for (int w = 0; w < 16; ++w) sum += red[w*RSTR + tid];
        const int c = tid >> 6;
        sZ[tid] = 1.f / (1.f + expf(-(sum + xpre[1][tid] + sBias[4 + c])));
      } else if (tid < 384){
        const int idx = tid - 256;
        float sum = 0.f;
        #pragma unroll
        for (int w = 0; w < 16; ++w) sum += red[w*RSTR + tid];
        const int oc = idx >> 6, bl = idx & 63;
        if (t > 0)
          out[((size_t)(t-1)*BB + bl)*OO + o0 + oc] = sum + sBias[12 + oc];
      }
      if (tid == 0) g_wait(bars, 2*t + 1);
      __syncthreads();

      // ================= B: candidate + h update =================
      {
        float aH[4][4] = {};
        const float* sb = s + kh0 * BB + b0;
        #pragma unroll
        for (int i4 = 0; i4 < 4; ++i4){
          f4 sv4[4];
          ldc4(sb + i4*4*BB, sv4);
          const int kxc = swz(kh0 + i4*4);
          #pragma unroll
          for (int c = 0; c < 4; ++c){
            f4 wf = *reinterpret_cast<const f4*>(&sW[2*4096 + c*1024 + kxc]);
            float wvv[4] = {wf.x, wf.y, wf.z, wf.w};
            #pragma unroll
            for (int kk = 0; kk < 4; ++kk){
              const f4 sv = sv4[kk];
              aH[c][0] = fmaf(wvv[kk], sv.x, aH[c][0]);
              aH[c][1] = fmaf(wvv[kk], sv.y, aH[c][1]);
              aH[c][2] = fmaf(wvv[kk], sv.z, aH[c][2]);
              aH[c][3] = fmaf(wvv[kk], sv.w, aH[c][3]);
            }
          }
        }
        #pragma unroll
        for (int c = 0; c < 4; ++c)
          #pragma unroll
          for (int bb = 0; bb < 4; ++bb) WREDUCE(aH[c][bb]);
        if (wr0)
          #pragma unroll
          for (int c = 0; c < 4; ++c)
            #pragma unroll
            for (int bb = 0; bb < 4; ++bb)
              red[wv*RSTR + c*64 + b0 + bb] = aH[c][bb];
      }
      __syncthreads();
      if (tid < 256){
        float sum = 0.f;
        #pragma unroll
        for (int w = 0; w < 16; ++w) sum += red[w*RSTR + tid];
        const int c = tid >> 6, bl = tid & 63;
        const int jg = j0 + c;
        const float ht = tanhf(sum + xpre[2][tid] + sBias[8 + c]);
        const float z = sZ[tid];
        const float hold = ldc1(&h[jg*BB + bl]);
        const float hnew = fmaf(z, ht - hold, hold);
        stc1(&h[jg*BB + bl], hnew);
        if (t == TT - 1) out[(size_t)TT*BB*OO + (size_t)bl*HH + jg] = hnew;
      }
      __syncthreads();
      if (tid == 0) g_arrive(bars, bid, 2*t + 2);
    }

    // ==== C: x-projections for step t+1, 3 single-gate passes (hide barrier B) ====
    if (t + 1 < TT){
      const int tc = t + 1;
      const float* xb = xT + (size_t)tc * II * BB + kx0 * BB + b0;
      #pragma unroll
      for (int g = 0; g < 3; ++g){
        const float* Wg = (g == 0) ? WxTr : (g == 1) ? WxTz : WxTh;
        {
          float aX[4][4] = {};
          #pragma unroll
          for (int i4 = 0; i4 < 2; ++i4){
            f4 xv4[4];
            #pragma unroll
            for (int kk = 0; kk < 4; ++kk) xv4[kk] = ld4(xb + (i4*4+kk) * BB);
            #pragma unroll
            for (int c = 0; c < 4; ++c){
              f4 wf = ld4(Wg + (size_t)(j0 + c) * II + kx0 + i4*4);
              float wvv[4] = {wf.x, wf.y, wf.z, wf.w};
              #pragma unroll
              for (int kk = 0; kk < 4; ++kk){
                const f4 xv = xv4[kk];
                aX[c][0] = fmaf(wvv[kk], xv.x, aX[c][0]);
                aX[c][1] = fmaf(wvv[kk], xv.y, aX[c][1]);
                aX[c][2] = fmaf(wvv[kk], xv.z, aX[c][2]);
                aX[c][3] = fmaf(wvv[kk], xv.w, aX[c][3]);
              }
            }
          }
          #pragma unroll
          for (int c = 0; c < 4; ++c)
            #pragma unroll
            for (int bb = 0; bb < 4; ++bb) WREDUCE(aX[c][bb]);
          if (wr0)
            #pragma unroll
            for (int c = 0; c < 4; ++c)
              #pragma unroll
              for (int bb = 0; bb < 4; ++bb)
                red[wv*RSTR + c*64 + b0 + bb] = aX[c][bb];
        }
        __syncthreads();
        if (tid < 256){
          float sum = 0.f;
          #pragma unroll
          for (int w = 0; w < 16; ++w) sum += red[w*RSTR + tid];
          xpre[g][tid] = sum;
        }
        __syncthreads();
      }
    }

    if (t >= 0){
      if (tid == 0) g_wait(bars, 2*t + 2);
      __syncthreads();
    }
  }

  // ================= trailing y_{T-1} from final h =================
  {
    float aY[2][4] = {};
    const float* hb = h + kh0 * BB + b0;
    #pragma unroll
    for (int i4 = 0; i4 < 4; ++i4){
      f4 hv4[4];
      ldc4(hb + i4*4*BB, hv4);
      const int kc = kh0 + i4*4;
      #pragma unroll
      for (int oc = 0; oc < 2; ++oc){
        f4 wo = ld4(W_out + (size_t)(o0 + oc) * HH + kc);
        float wvv[4] = {wo.x, wo.y, wo.z, wo.w};
        #pragma unroll
        for (int kk = 0; kk < 4; ++kk){
          const f4 hv = hv4[kk];
          aY[oc][0] = fmaf(wvv[kk], hv.x, aY[oc][0]);
          aY[oc][1] = fmaf(wvv[kk], hv.y, aY[oc][1]);
          aY[oc][2] = fmaf(wvv[kk], hv.z, aY[oc][2]);
          aY[oc][3] = fmaf(wvv[kk], hv.w, aY[oc][3]);
        }
      }
    }
    #pragma unroll
    for (int oc = 0; oc < 2; ++oc)
      #pragma unroll
      for (int bb = 0; bb < 4; ++bb) WREDUCE(aY[oc][bb]);
    if (wr0)
      #pragma unroll
      for (int oc = 0; oc < 2; ++oc)
        #pragma unroll
        for (int bb = 0; bb < 4; ++bb)
          red[wv*RSTR + oc*64 + b0 + bb] = aY[oc][bb];
    __syncthreads();
    if (tid < 128){
      float sum = 0.f;
      #pragma unroll
      for (int w = 0; w < 16; ++w) sum += red[w*RSTR + tid];
      const int oc = tid >> 6, bl = tid & 63;
      out[((size_t)(TT-1)*BB + bl)*OO + o0 + oc] = sum + sBias[12 + oc];
    }
  }
}

// ---------------- host ----------------
extern "C" void kernel_launch(void* const* d_in, const int* in_sizes, int n_in,
                              void* d_out, int out_size, void* d_ws, size_t ws_size,
                              hipStream_t stream) {
  const float* x     = (const float*)d_in[0];
  const float* st    = (const float*)d_in[1];
  const float* W_zh  = (const float*)d_in[2];
  const float* W_zx  = (const float*)d_in[3];
  const float* b_z   = (const float*)d_in[4];
  const float* W_rh  = (const float*)d_in[5];
  const float* W_rx  = (const float*)d_in[6];
  const float* b_r   = (const float*)d_in[7];
  const float* W_hh  = (const float*)d_in[8];
  const float* W_hx  = (const float*)d_in[9];
  const float* b_h   = (const float*)d_in[10];
  const float* W_out = (const float*)d_in[11];
  const float* b_out = (const float*)d_in[12];
  float* out = (float*)d_out;
  float* ws  = (float*)d_ws;

  const size_t xT_sz = (size_t)TT * II * BB;   // 16,777,216
  const size_t wx_sz = (size_t)II * HH;        //    524,288
  const size_t h_sz  = (size_t)HH * BB;        //     65,536
  const size_t need  = (xT_sz + 3*wx_sz + 2*h_sz) * sizeof(float) + 512*sizeof(unsigned);
  if (ws_size < need) return;

  float* xT   = ws;
  float* WxTr = xT + xT_sz;
  float* WxTz = WxTr + wx_sz;
  float* WxTh = WxTz + wx_sz;
  float* h    = WxTh + wx_sz;
  float* s    = h + h_sz;
  unsigned* bars = (unsigned*)(s + h_sz);

  k_transpose_x <<<8192, 256, 0, stream>>>(x, xT);
  k_transpose_wx<<<2048, 256, 0, stream>>>(W_rx, WxTr);
  k_transpose_wx<<<2048, 256, 0, stream>>>(W_zx, WxTz);
  k_transpose_wx<<<2048, 256, 0, stream>>>(W_hx, WxTh);
  k_transpose_h0<<< 256, 256, 0, stream>>>(st, h);
  k_init_bars   <<<   1, 512, 0, stream>>>(bars);

  k_gru<<<NBLK, NTHR, 0, stream>>>(xT, WxTr, WxTz, WxTh, h, s,
                                   W_zh, b_z, W_rh, b_r, W_hh, b_h,
                                   W_out, b_out, out, bars);
}

// Round 15
// 14529.378 us; speedup vs baseline: 1.0454x; 1.0454x over previous
//
#include <hip/hip_runtime.h>
#include <cstdint>

// GRU persistent kernel v13: T=512, B=64, I=512, H=1024, O=512, fp32.
// 256 blocks (1/CU, all resident, single barrier group) x 1024 thr
// (16 waves/CU = 4/SIMD, designed for the fixed 64-VGPR budget).
// Changes vs v12 (15.8 ms, FETCH 12.6 GB):
//  - P1 merges r+z+y into ONE coherent h pass (aR+aZ+aY ~56 live floats);
//    one combined reduce round (640 epilogue lanes). Removes A2 entirely
//    (and with it v12's latent read-after-arrive race on h).
//  - Ping-pong h buffers: step t reads buf[t&1], writes buf[(t+1)&1];
//    y_{t-1} reads the stable input buffer.
//  - P2 streams s with 8-deep batched coherent loads (2 RTs, not 4).
//  - xpre shadow passes: r,z hide barrier A; h-gate hides barrier B.
// Coherent h/s exchange via sc0 sc1 (L2-bypass) + relaxed barrier
// (v9/v12-validated). Weights (3 h-gates) in 48 KB swizzled LDS.

#define TT 512
#define BB 64
#define II 512
#define HH 1024
#define OO 512
#define NTHR 1024
#define NBLK 256
#define RSTR 656

typedef float4 f4;
__device__ __forceinline__ f4 ld4(const float* p){ return *reinterpret_cast<const f4*>(p); }
__device__ __forceinline__ int swz(int k){ return k ^ (((k >> 4) & 7) << 2); }

// ---- coherent (L2-bypass, L3-served) access helpers for h/s ----
__device__ __forceinline__ void ldc4(const float* p, f4* d){
  asm volatile(
    "global_load_dwordx4 %0, %4, off sc0 sc1\n\t"
    "global_load_dwordx4 %1, %4, off offset:256 sc0 sc1\n\t"
    "global_load_dwordx4 %2, %4, off offset:512 sc0 sc1\n\t"
    "global_load_dwordx4 %3, %4, off offset:768 sc0 sc1\n\t"
    "s_waitcnt vmcnt(0)"
    : "=&v"(d[0]),"=&v"(d[1]),"=&v"(d[2]),"=&v"(d[3])
    : "v"(p) : "memory");
}
__device__ __forceinline__ void ldc8(const float* p, f4* d){
  asm volatile(
    "global_load_dwordx4 %0, %8, off sc0 sc1\n\t"
    "global_load_dwordx4 %1, %8, off offset:256 sc0 sc1\n\t"
    "global_load_dwordx4 %2, %8, off offset:512 sc0 sc1\n\t"
    "global_load_dwordx4 %3, %8, off offset:768 sc0 sc1\n\t"
    "global_load_dwordx4 %4, %8, off offset:1024 sc0 sc1\n\t"
    "global_load_dwordx4 %5, %8, off offset:1280 sc0 sc1\n\t"
    "global_load_dwordx4 %6, %8, off offset:1536 sc0 sc1\n\t"
    "global_load_dwordx4 %7, %8, off offset:1792 sc0 sc1\n\t"
    "s_waitcnt vmcnt(0)"
    : "=&v"(d[0]),"=&v"(d[1]),"=&v"(d[2]),"=&v"(d[3]),
      "=&v"(d[4]),"=&v"(d[5]),"=&v"(d[6]),"=&v"(d[7])
    : "v"(p) : "memory");
}
__device__ __forceinline__ float ldc1(const float* p){
  float v;
  asm volatile("global_load_dword %0, %1, off sc0 sc1\n\ts_waitcnt vmcnt(0)"
               : "=v"(v) : "v"(p) : "memory");
  return v;
}
__device__ __forceinline__ void stc1(float* p, float v){
  asm volatile("global_store_dword %0, %1, off sc0 sc1" :: "v"(p), "v"(v) : "memory");
}

// ---------------- one-time prep kernels ----------------
__global__ void k_transpose_x(const float* __restrict__ x, float* __restrict__ xT){
  size_t total = (size_t)TT * II * BB;
  for (size_t n = (size_t)blockIdx.x * blockDim.x + threadIdx.x; n < total;
       n += (size_t)gridDim.x * blockDim.x){
    size_t t = n / ((size_t)II * BB);
    size_t rem = n % ((size_t)II * BB);
    size_t i = rem / BB, b = rem % BB;
    xT[n] = x[(t * BB + b) * II + i];
  }
}

__global__ void k_transpose_wx(const float* __restrict__ W, float* __restrict__ WT){
  size_t n = (size_t)blockIdx.x * blockDim.x + threadIdx.x;
  if (n >= (size_t)II * HH) return;
  size_t j = n / II, k = n % II;
  WT[n] = W[k * HH + j];
}

__global__ void k_transpose_h0(const float* __restrict__ st, float* __restrict__ h0){
  size_t n = (size_t)blockIdx.x * blockDim.x + threadIdx.x;
  if (n >= (size_t)HH * BB) return;
  size_t j = n / BB, b = n % BB;
  h0[n] = st[b * HH + j];
}

__global__ void k_init_bars(unsigned* bars){
  if (threadIdx.x < 512) bars[threadIdx.x] = 0;
}

// --- barrier: ONE group of 256 blocks; 16 leaves x 16 arrivals; RELAXED ---
__device__ __forceinline__ void g_arrive(unsigned* bars, int bid, unsigned ep){
  asm volatile("s_waitcnt vmcnt(0)" ::: "memory");   // drain sc1 data stores
  unsigned* leaf = bars + (bid & 15) * 16;
  unsigned old = __hip_atomic_fetch_add(leaf, 1u, __ATOMIC_RELAXED, __HIP_MEMORY_SCOPE_AGENT);
  if (old + 1u == ep * 16u)
    __hip_atomic_fetch_add(bars + 256, 1u, __ATOMIC_RELAXED, __HIP_MEMORY_SCOPE_AGENT);
}
__device__ __forceinline__ void g_wait(unsigned* bars, unsigned ep){
  while (__hip_atomic_load(bars + 256, __ATOMIC_RELAXED, __HIP_MEMORY_SCOPE_AGENT) < ep * 16u)
    __builtin_amdgcn_s_sleep(1);
}

// in-wave ksec bits = tid bits [5:4]
#define WREDUCE(v) { v += __shfl_xor(v, 16); v += __shfl_xor(v, 32); }

// ---------------- the persistent GRU kernel ----------------
__global__ __launch_bounds__(NTHR) void k_gru(
    const float* __restrict__ xT,
    const float* __restrict__ WxTr, const float* __restrict__ WxTz, const float* __restrict__ WxTh,
    float* __restrict__ h0buf, float* __restrict__ h1buf, float* __restrict__ s,
    const float* __restrict__ W_zh, const float* __restrict__ b_z,
    const float* __restrict__ W_rh, const float* __restrict__ b_r,
    const float* __restrict__ W_hh, const float* __restrict__ b_h,
    const float* __restrict__ W_out, const float* __restrict__ b_out,
    float* __restrict__ out, unsigned* __restrict__ bars)
{
  __shared__ float sW[3 * 4 * 1024];   // [0=RH,1=ZH,2=HH][c<4][k swz]  48 KB
  __shared__ float red[16 * RSTR];     // cross-wave reduce             42 KB
  __shared__ float xpre[3][256];       // x-projections (4c x 64b)
  __shared__ float sZ[256];            // z gate
  __shared__ float sBias[16];          // b_r[4] b_z[4] b_h[4] b_out[2]

  const int tid = threadIdx.x;
  const int bid = blockIdx.x;
  const int j0 = bid * 4, o0 = bid * 2;

  // ---- prologue: weight slices -> swizzled LDS (one k per thread) ----
  {
    const int k = tid;                 // 0..1023
    f4 vr = ld4(W_rh + (size_t)k * HH + j0);
    f4 vz = ld4(W_zh + (size_t)k * HH + j0);
    f4 vh = ld4(W_hh + (size_t)k * HH + j0);
    const int kx = swz(k);
    float ar[4] = {vr.x,vr.y,vr.z,vr.w};
    float az[4] = {vz.x,vz.y,vz.z,vz.w};
    float ah[4] = {vh.x,vh.y,vh.z,vh.w};
    #pragma unroll
    for (int c = 0; c < 4; ++c){
      sW[0*4096 + c*1024 + kx] = ar[c];
      sW[1*4096 + c*1024 + kx] = az[c];
      sW[2*4096 + c*1024 + kx] = ah[c];
    }
  }
  if (tid < 4){
    sBias[tid]     = b_r[j0 + tid];
    sBias[4 + tid] = b_z[j0 + tid];
    sBias[8 + tid] = b_h[j0 + tid];
    if (tid < 2) sBias[12 + tid] = b_out[o0 + tid];
  }

  const int bg = tid & 15, b0 = bg * 4;      // 16 groups x 4 b = full 64
  const int ksec = tid >> 4;                 // 0..63
  const int wv = tid >> 6;                   // wave 0..15
  const bool wr0 = ((tid & 48) == 0);
  const int kh0 = ksec * 16;                 // K=1024 / 64
  const int kx0 = ksec * 8;                  // K=512  / 64
  __syncthreads();

  // xpre shadow pass macro: gate g (0=r,1=z,2=h), for step tc
  #define XPRE(g_, tc_) do {                                                 \
    const float* xb_ = xT + (size_t)(tc_) * II * BB + kx0 * BB + b0;         \
    const float* Wg_ = ((g_) == 0) ? WxTr : ((g_) == 1) ? WxTz : WxTh;       \
    float aX_[4][4] = {};                                                    \
    _Pragma("unroll")                                                        \
    for (int i4 = 0; i4 < 2; ++i4){                                          \
      f4 xv4_[4];                                                            \
      _Pragma("unroll")                                                      \
      for (int kk = 0; kk < 4; ++kk) xv4_[kk] = ld4(xb_ + (i4*4+kk) * BB);   \
      _Pragma("unroll")                                                      \
      for (int c = 0; c < 4; ++c){                                           \
        f4 wf_ = ld4(Wg_ + (size_t)(j0 + c) * II + kx0 + i4*4);              \
        float wvv_[4] = {wf_.x, wf_.y, wf_.z, wf_.w};                        \
        _Pragma("unroll")                                                    \
        for (int kk = 0; kk < 4; ++kk){                                      \
          const f4 xv_ = xv4_[kk];                                           \
          aX_[c][0] = fmaf(wvv_[kk], xv_.x, aX_[c][0]);                      \
          aX_[c][1] = fmaf(wvv_[kk], xv_.y, aX_[c][1]);                      \
          aX_[c][2] = fmaf(wvv_[kk], xv_.z, aX_[c][2]);                      \
          aX_[c][3] = fmaf(wvv_[kk], xv_.w, aX_[c][3]);                      \
        }                                                                    \
      }                                                                      \
    }                                                                        \
    _Pragma("unroll")                                                        \
    for (int c = 0; c < 4; ++c)                                              \
      _Pragma("unroll")                                                      \
      for (int bb = 0; bb < 4; ++bb) WREDUCE(aX_[c][bb]);                    \
    if (wr0)                                                                 \
      _Pragma("unroll")                                                      \
      for (int c = 0; c < 4; ++c)                                            \
        _Pragma("unroll")                                                    \
        for (int bb = 0; bb < 4; ++bb)                                       \
          red[wv*RSTR + c*64 + b0 + bb] = aX_[c][bb];                        \
    __syncthreads();                                                         \
    if (tid < 256){                                                          \
      float sum_ = 0.f;                                                      \
      _Pragma("unroll")                                                      \
      for (int w = 0; w < 16; ++w) sum_ += red[w*RSTR + tid];                \
      xpre[g_][tid] = sum_;                                                  \
    }                                                                        \
    __syncthreads();                                                         \
  } while (0)

  for (int t = -1; t < TT; ++t){
    if (t < 0){
      XPRE(0, 0); XPRE(1, 0); XPRE(2, 0);
      continue;
    }
    const float* hin = (t & 1) ? h1buf : h0buf;
    float*       hout = (t & 1) ? h0buf : h1buf;
    const float* hb = hin + kh0 * BB + b0;

    // ===== P1: r + z + y_{t-1} from ONE coherent h pass =====
    {
      float aR[4][4] = {}, aZ[4][4] = {}, aY[2][4] = {};
      #pragma unroll
      for (int i4 = 0; i4 < 4; ++i4){
        f4 hv4[4];
        ldc4(hb + i4*4*BB, hv4);
        const int kc = kh0 + i4*4;
        const int kxc = swz(kc);
        #pragma unroll
        for (int c = 0; c < 4; ++c){
          f4 wr_ = *reinterpret_cast<const f4*>(&sW[0*4096 + c*1024 + kxc]);
          f4 wz_ = *reinterpret_cast<const f4*>(&sW[1*4096 + c*1024 + kxc]);
          float wrv[4] = {wr_.x, wr_.y, wr_.z, wr_.w};
          float wzv[4] = {wz_.x, wz_.y, wz_.z, wz_.w};
          #pragma unroll
          for (int kk = 0; kk < 4; ++kk){
            const f4 hv = hv4[kk];
            aR[c][0] = fmaf(wrv[kk], hv.x, aR[c][0]);
            aR[c][1] = fmaf(wrv[kk], hv.y, aR[c][1]);
            aR[c][2] = fmaf(wrv[kk], hv.z, aR[c][2]);
            aR[c][3] = fmaf(wrv[kk], hv.w, aR[c][3]);
            aZ[c][0] = fmaf(wzv[kk], hv.x, aZ[c][0]);
            aZ[c][1] = fmaf(wzv[kk], hv.y, aZ[c][1]);
            aZ[c][2] = fmaf(wzv[kk], hv.z, aZ[c][2]);
            aZ[c][3] = fmaf(wzv[kk], hv.w, aZ[c][3]);
          }
        }
        #pragma unroll
        for (int oc = 0; oc < 2; ++oc){
          f4 wo = ld4(W_out + (size_t)(o0 + oc) * HH + kc);   // read-only, L2-hot
          float wvv[4] = {wo.x, wo.y, wo.z, wo.w};
          #pragma unroll
          for (int kk = 0; kk < 4; ++kk){
            const f4 hv = hv4[kk];
            aY[oc][0] = fmaf(wvv[kk], hv.x, aY[oc][0]);
            aY[oc][1] = fmaf(wvv[kk], hv.y, aY[oc][1]);
            aY[oc][2] = fmaf(wvv[kk], hv.z, aY[oc][2]);
            aY[oc][3] = fmaf(wvv[kk], hv.w, aY[oc][3]);
          }
        }
      }
      #pragma unroll
      for (int c = 0; c < 4; ++c)
        #pragma unroll
        for (int bb = 0; bb < 4; ++bb){ WREDUCE(aR[c][bb]); WREDUCE(aZ[c][bb]); }
      #pragma unroll
      for (int oc = 0; oc < 2; ++oc)
        #pragma unroll
        for (int bb = 0; bb < 4; ++bb) WREDUCE(aY[oc][bb]);
      if (wr0){
        #pragma unroll
        for (int c = 0; c < 4; ++c)
          #pragma unroll
          for (int bb = 0; bb < 4; ++bb){
            red[wv*RSTR + c*64 + b0 + bb]       = aR[c][bb];
            red[wv*RSTR + 256 + c*64 + b0 + bb] = aZ[c][bb];
          }
        #pragma unroll
        for (int oc = 0; oc < 2; ++oc)
          #pragma unroll
          for (int bb = 0; bb < 4; ++bb)
            red[wv*RSTR + 512 + oc*64 + b0 + bb] = aY[oc][bb];
      }
    }
    __syncthreads();
    if (tid < 256){
      float sum = 0.f;
      #pragma unroll
      for (int w = 0; w < 16; ++w) sum += red[w*RSTR + tid];
      const int c = tid >> 6, bl = tid & 63;
      const float v = sum + xpre[0][tid] + sBias[c];
      const float rr = 1.f / (1.f + expf(-v));
      const int jg = j0 + c;
      stc1(&s[jg*BB + bl], rr * ldc1(&hin[jg*BB + bl]));
    } else if (tid < 512){
      const int idx = tid - 256;
      float sum = 0.f;
      #pragma unroll
      for (int w = 0; w < 16; ++w) sum += red[w*RSTR + tid];
      const int c = idx >> 6;
      sZ[idx] = 1.f / (1.f + expf(-(sum + xpre[1][idx] + sBias[4 + c])));
    } else if (tid < 640){
      const int idx = tid - 512;
      float sum = 0.f;
      #pragma unroll
      for (int w = 0; w < 16; ++w) sum += red[w*RSTR + tid];
      const int oc = idx >> 6, bl = idx & 63;
      if (t > 0)
        out[((size_t)(t-1)*BB + bl)*OO + o0 + oc] = sum + sBias[12 + oc];
    }
    __syncthreads();                       // drains s stores per-wave
    if (tid == 0) g_arrive(bars, bid, 2*t + 1);

    // ===== shadow-A: xpre r,z for t+1 (hides barrier A) =====
    if (t + 1 < TT){ XPRE(0, t+1); XPRE(1, t+1); }
    if (tid == 0) g_wait(bars, 2*t + 1);
    __syncthreads();

    // ===== P2: candidate + h update (8-deep batched s reads) =====
    {
      float aH[4][4] = {};
      const float* sb = s + kh0 * BB + b0;
      #pragma unroll
      for (int i8 = 0; i8 < 2; ++i8){
        f4 sv8[8];
        ldc8(sb + i8*8*BB, sv8);
        #pragma unroll
        for (int q = 0; q < 2; ++q){
          const int kxc = swz(kh0 + i8*8 + q*4);
          #pragma unroll
          for (int c = 0; c < 4; ++c){
            f4 wf = *reinterpret_cast<const f4*>(&sW[2*4096 + c*1024 + kxc]);
            float wvv[4] = {wf.x, wf.y, wf.z, wf.w};
            #pragma unroll
            for (int kk = 0; kk < 4; ++kk){
              const f4 sv = sv8[q*4+kk];
              aH[c][0] = fmaf(wvv[kk], sv.x, aH[c][0]);
              aH[c][1] = fmaf(wvv[kk], sv.y, aH[c][1]);
              aH[c][2] = fmaf(wvv[kk], sv.z, aH[c][2]);
              aH[c][3] = fmaf(wvv[kk], sv.w, aH[c][3]);
            }
          }
        }
      }
      #pragma unroll
      for (int c = 0; c < 4; ++c)
        #pragma unroll
        for (int bb = 0; bb < 4; ++bb) WREDUCE(aH[c][bb]);
      if (wr0)
        #pragma unroll
        for (int c = 0; c < 4; ++c)
          #pragma unroll
          for (int bb = 0; bb < 4; ++bb)
            red[wv*RSTR + c*64 + b0 + bb] = aH[c][bb];
    }
    __syncthreads();
    if (tid < 256){
      float sum = 0.f;
      #pragma unroll
      for (int w = 0; w < 16; ++w) sum += red[w*RSTR + tid];
      const int c = tid >> 6, bl = tid & 63;
      const int jg = j0 + c;
      const float ht = tanhf(sum + xpre[2][tid] + sBias[8 + c]);
      const float z = sZ[tid];
      const float hold = ldc1(&hin[jg*BB + bl]);
      const float hnew = fmaf(z, ht - hold, hold);
      stc1(&hout[jg*BB + bl], hnew);
      if (t == TT - 1) out[(size_t)TT*BB*OO + (size_t)bl*HH + jg] = hnew;
    }
    __syncthreads();                       // drains h stores per-wave
    if (tid == 0) g_arrive(bars, bid, 2*t + 2);

    // ===== shadow-B: xpre h-gate for t+1 (hides barrier B) =====
    if (t + 1 < TT) XPRE(2, t+1);
    if (tid == 0) g_wait(bars, 2*t + 2);
    __syncthreads();
  }

  // ================= trailing y_{TT-1} from final h (buf[TT&1] = h0buf) ====
  {
    const float* hfin = (TT & 1) ? h1buf : h0buf;
    const float* hb = hfin + kh0 * BB + b0;
    float aY[2][4] = {};
    #pragma unroll
    for (int i4 = 0; i4 < 4; ++i4){
      f4 hv4[4];
      ldc4(hb + i4*4*BB, hv4);
      const int kc = kh0 + i4*4;
      #pragma unroll
      for (int oc = 0; oc < 2; ++oc){
        f4 wo = ld4(W_out + (size_t)(o0 + oc) * HH + kc);
        float wvv[4] = {wo.x, wo.y, wo.z, wo.w};
        #pragma unroll
        for (int kk = 0; kk < 4; ++kk){
          const f4 hv = hv4[kk];
          aY[oc][0] = fmaf(wvv[kk], hv.x, aY[oc][0]);
          aY[oc][1] = fmaf(wvv[kk], hv.y, aY[oc][1]);
          aY[oc][2] = fmaf(wvv[kk], hv.z, aY[oc][2]);
          aY[oc][3] = fmaf(wvv[kk], hv.w, aY[oc][3]);
        }
      }
    }
    #pragma unroll
    for (int oc = 0; oc < 2; ++oc)
      #pragma unroll
      for (int bb = 0; bb < 4; ++bb) WREDUCE(aY[oc][bb]);
    if (wr0)
      #pragma unroll
      for (int oc = 0; oc < 2; ++oc)
        #pragma unroll
        for (int bb = 0; bb < 4; ++bb)
          red[wv*RSTR + oc*64 + b0 + bb] = aY[oc][bb];
    __syncthreads();
    if (tid < 128){
      float sum = 0.f;
      #pragma unroll
      for (int w = 0; w < 16; ++w) sum += red[w*RSTR + tid];
      const int oc = tid >> 6, bl = tid & 63;
      out[((size_t)(TT-1)*BB + bl)*OO + o0 + oc] = sum + sBias[12 + oc];
    }
  }
  #undef XPRE
}

// ---------------- host ----------------
extern "C" void kernel_launch(void* const* d_in, const int* in_sizes, int n_in,
                              void* d_out, int out_size, void* d_ws, size_t ws_size,
                              hipStream_t stream) {
  const float* x     = (const float*)d_in[0];
  const float* st    = (const float*)d_in[1];
  const float* W_zh  = (const float*)d_in[2];
  const float* W_zx  = (const float*)d_in[3];
  const float* b_z   = (const float*)d_in[4];
  const float* W_rh  = (const float*)d_in[5];
  const float* W_rx  = (const float*)d_in[6];
  const float* b_r   = (const float*)d_in[7];
  const float* W_hh  = (const float*)d_in[8];
  const float* W_hx  = (const float*)d_in[9];
  const float* b_h   = (const float*)d_in[10];
  const float* W_out = (const float*)d_in[11];
  const float* b_out = (const float*)d_in[12];
  float* out = (float*)d_out;
  float* ws  = (float*)d_ws;

  const size_t xT_sz = (size_t)TT * II * BB;   // 16,777,216
  const size_t wx_sz = (size_t)II * HH;        //    524,288
  const size_t h_sz  = (size_t)HH * BB;        //     65,536
  const size_t need  = (xT_sz + 3*wx_sz + 3*h_sz) * sizeof(float) + 512*sizeof(unsigned);
  if (ws_size < need) return;

  float* xT   = ws;
  float* WxTr = xT + xT_sz;
  float* WxTz = WxTr + wx_sz;
  float* WxTh = WxTz + wx_sz;
  float* hb0  = WxTh + wx_sz;
  float* hb1  = hb0 + h_sz;
  float* s    = hb1 + h_sz;
  unsigned* bars = (unsigned*)(s + h_sz);

  k_transpose_x <<<8192, 256, 0, stream>>>(x, xT);
  k_transpose_wx<<<2048, 256, 0, stream>>>(W_rx, WxTr);
  k_transpose_wx<<<2048, 256, 0, stream>>>(W_zx, WxTz);
  k_transpose_wx<<<2048, 256, 0, stream>>>(W_hx, WxTh);
  k_transpose_h0<<< 256, 256, 0, stream>>>(st, hb0);
  k_init_bars   <<<   1, 512, 0, stream>>>(bars);

  k_gru<<<NBLK, NTHR, 0, stream>>>(xT, WxTr, WxTz, WxTh, hb0, hb1, s,
                                   W_zh, b_z, W_rh, b_r, W_hh, b_h,
                                   W_out, b_out, out, bars);
}